// Round 1
// baseline (442.563 us; speedup 1.0000x reference)
//
#include <hip/hip_runtime.h>

#define U_NODES 200000
#define B_ROWS  20000
#define K_S     33
#define F_DIM   256
#define E_DIM   128

constexpr int BM = 128;   // rows per block
constexpr int BK = 32;    // k-slice per stage; BN = E_DIM = 128 (full width)
constexpr int LDA = BM + 4;     // padded LDS strides (keep 16B alignment: stride%4==0)
constexpr int LDB = E_DIM + 4;

// ---------------------------------------------------------------------------
// GEMM h = A @ W  (bias omitted — it cancels in BatchNorm), with fused
// per-column sum / sum-of-squares accumulation for BN batch statistics.
// Block tile: 128 rows x 128 cols, K staged in 32-wide slices.
// Thread tile: 8x8 (256 threads = 16x16 thread grid).
// ---------------------------------------------------------------------------
__global__ __launch_bounds__(256) void gemm_stats_kernel(
    const float* __restrict__ A,    // [U, F]
    const float* __restrict__ W,    // [F, E]
    float* __restrict__ h,          // [U, E]
    float* __restrict__ gsum,       // [E]
    float* __restrict__ gsq)        // [E]
{
    __shared__ float As[BK][LDA];   // k-major (transposed) A tile: As[k][m]
    __shared__ float Bs[BK][LDB];   // row-major W tile: Bs[k][n]

    const int t    = threadIdx.x;
    const int tx   = t & 15;        // col group: cols tx*8 .. tx*8+7
    const int ty   = t >> 4;        // row group: rows ty*8 .. ty*8+7
    const int row0 = blockIdx.x * BM;

    float acc[8][8];
    #pragma unroll
    for (int i = 0; i < 8; ++i)
        #pragma unroll
        for (int j = 0; j < 8; ++j) acc[i][j] = 0.f;

    for (int kk = 0; kk < F_DIM; kk += BK) {
        // Stage A tile [BM x BK] transposed into As[k][m]: 4096 floats, 4 float4/thread
        #pragma unroll
        for (int l = 0; l < 4; ++l) {
            int q = t + 256 * l;        // 0..1023
            int r = q >> 3;             // tile row 0..127 (8 float4 per row)
            int c = (q & 7) * 4;        // tile col (k within slice)
            int gr = row0 + r;
            if (gr >= U_NODES) gr = U_NODES - 1;   // clamp; garbage rows never stored
            float4 v = *(const float4*)(A + (size_t)gr * F_DIM + kk + c);
            As[c + 0][r] = v.x;
            As[c + 1][r] = v.y;
            As[c + 2][r] = v.z;
            As[c + 3][r] = v.w;
        }
        // Stage W tile [BK x E] row-major: 4096 floats, 4 float4/thread
        #pragma unroll
        for (int l = 0; l < 4; ++l) {
            int q = t + 256 * l;
            int r = q >> 5;             // 32 float4 per row
            int c = (q & 31) * 4;
            float4 v = *(const float4*)(W + (size_t)(kk + r) * E_DIM + c);
            *(float4*)&Bs[r][c] = v;
        }
        __syncthreads();

        #pragma unroll
        for (int k = 0; k < BK; ++k) {
            float av[8], bv[8];
            *(float4*)&av[0] = *(const float4*)&As[k][ty * 8];
            *(float4*)&av[4] = *(const float4*)&As[k][ty * 8 + 4];
            *(float4*)&bv[0] = *(const float4*)&Bs[k][tx * 8];
            *(float4*)&bv[4] = *(const float4*)&Bs[k][tx * 8 + 4];
            #pragma unroll
            for (int i = 0; i < 8; ++i)
                #pragma unroll
                for (int j = 0; j < 8; ++j)
                    acc[i][j] = fmaf(av[i], bv[j], acc[i][j]);
        }
        __syncthreads();
    }

    // Epilogue: store h and accumulate per-column stats (no bias — cancels in BN)
    float s[8], sq[8];
    #pragma unroll
    for (int j = 0; j < 8; ++j) { s[j] = 0.f; sq[j] = 0.f; }
    #pragma unroll
    for (int i = 0; i < 8; ++i) {
        int gr = row0 + ty * 8 + i;
        if (gr < U_NODES) {
            float* hp = h + (size_t)gr * E_DIM + tx * 8;
            *(float4*)(hp)     = make_float4(acc[i][0], acc[i][1], acc[i][2], acc[i][3]);
            *(float4*)(hp + 4) = make_float4(acc[i][4], acc[i][5], acc[i][6], acc[i][7]);
            #pragma unroll
            for (int j = 0; j < 8; ++j) { float v = acc[i][j]; s[j] += v; sq[j] += v * v; }
        }
    }

    // Reduce the 16 ty-groups per column via LDS (reuse As storage), then one atomic/column
    float* red = &As[0][0];     // needs 16*128 = 2048 floats <= BK*LDA
    #pragma unroll
    for (int j = 0; j < 8; ++j) red[ty * E_DIM + tx * 8 + j] = s[j];
    __syncthreads();
    if (t < E_DIM) {
        float tot = 0.f;
        #pragma unroll
        for (int r = 0; r < 16; ++r) tot += red[r * E_DIM + t];
        atomicAdd(&gsum[t], tot);
    }
    __syncthreads();
    #pragma unroll
    for (int j = 0; j < 8; ++j) red[ty * E_DIM + tx * 8 + j] = sq[j];
    __syncthreads();
    if (t < E_DIM) {
        float tot = 0.f;
        #pragma unroll
        for (int r = 0; r < 16; ++r) tot += red[r * E_DIM + t];
        atomicAdd(&gsq[t], tot);
    }
}

// ---------------------------------------------------------------------------
// Fold BN batch stats + gamma/beta into per-column scale/shift:
//   normalized = h*scale + shift;  scale = gamma*rsqrt(var+eps), shift = beta - scale*mu
// ---------------------------------------------------------------------------
__global__ void finalize_kernel(const float* __restrict__ gsum, const float* __restrict__ gsq,
                                const float* __restrict__ gamma, const float* __restrict__ beta,
                                float* __restrict__ scale, float* __restrict__ shift)
{
    int e = threadIdx.x;
    float mu  = gsum[e] * (1.f / U_NODES);
    float var = gsq[e] * (1.f / U_NODES) - mu * mu;
    float inv = rsqrtf(var + 1e-5f);
    float sc  = gamma[e] * inv;
    scale[e] = sc;
    shift[e] = beta[e] - sc * mu;
}

// ---------------------------------------------------------------------------
// Gather + BN-apply + tanh + mean over K=33 sampled rows.
// One 128-thread half-block per output row (2 rows / 256-thread block).
// tanh(x) = 1 - 2/(exp(2x)+1) via hw exp+rcp (abs err ~1e-6, NaN-free).
// ---------------------------------------------------------------------------
__global__ __launch_bounds__(256) void gather_kernel(
    const float* __restrict__ h, const int* __restrict__ sidx_g,
    const float* __restrict__ scale, const float* __restrict__ shift,
    float* __restrict__ out)
{
    const int e   = threadIdx.x & 127;
    const int sub = threadIdx.x >> 7;
    const int b   = blockIdx.x * 2 + sub;
    __shared__ int sidx[2][K_S];
    if (e < K_S) sidx[sub][e] = sidx_g[b * K_S + e];
    __syncthreads();
    const float sc = scale[e], sh = shift[e];
    float acc = 0.f;
    #pragma unroll
    for (int k = 0; k < K_S; ++k) {
        float x  = h[(size_t)sidx[sub][k] * E_DIM + e] * sc + sh;
        float ex = __expf(2.f * x);
        acc += 1.f - 2.f * __builtin_amdgcn_rcpf(ex + 1.f);
    }
    out[(size_t)b * E_DIM + e] = acc * (1.f / K_S);
}

// ---------------------------------------------------------------------------
extern "C" void kernel_launch(void* const* d_in, const int* in_sizes, int n_in,
                              void* d_out, int out_size, void* d_ws, size_t ws_size,
                              hipStream_t stream) {
    const float* features = (const float*)d_in[0];
    const float* W        = (const float*)d_in[1];
    // d_in[2] = bias b — provably cancels inside BatchNorm; unused.
    const float* gamma    = (const float*)d_in[3];
    const float* beta     = (const float*)d_in[4];
    const int*   sample   = (const int*)d_in[5];
    float* out = (float*)d_out;

    // workspace layout (floats): h [U*E] | gsum[E] | gsq[E] | scale[E] | shift[E]
    float* h     = (float*)d_ws;
    float* gsum  = h + (size_t)U_NODES * E_DIM;
    float* gsq   = gsum + E_DIM;
    float* scale = gsq + E_DIM;
    float* shift = scale + E_DIM;

    hipMemsetAsync(gsum, 0, 2 * E_DIM * sizeof(float), stream);

    dim3 g1((U_NODES + BM - 1) / BM);
    gemm_stats_kernel<<<g1, 256, 0, stream>>>(features, W, h, gsum, gsq);
    finalize_kernel<<<1, E_DIM, 0, stream>>>(gsum, gsq, gamma, beta, scale, shift);
    gather_kernel<<<B_ROWS / 2, 256, 0, stream>>>(h, sample, scale, shift, out);
}

// Round 2
// 344.405 us; speedup vs baseline: 1.2850x; 1.2850x over previous
//
#include <hip/hip_runtime.h>

#define U_NODES 200000
#define B_ROWS  20000
#define K_S     33
#define F_DIM   256
#define E_DIM   128

typedef __bf16 bf16x8 __attribute__((ext_vector_type(8)));
typedef float  f32x4  __attribute__((ext_vector_type(4)));
typedef unsigned short ushortx4 __attribute__((ext_vector_type(4)));
typedef unsigned short ushortx8 __attribute__((ext_vector_type(8)));

__device__ __forceinline__ unsigned short f2bf(float f) {
    unsigned int u = __builtin_bit_cast(unsigned int, f);
    u += 0x7fffu + ((u >> 16) & 1u);            // round-to-nearest-even
    return (unsigned short)(u >> 16);
}
__device__ __forceinline__ float bf2f(unsigned short s) {
    return __builtin_bit_cast(float, ((unsigned int)s) << 16);
}

// ---------------------------------------------------------------------------
// One-time prep: Wt[n][k] = bf16(W[k][n]), so GEMM B-fragments are
// contiguous-k 16B LDS reads. Tiny (32K elements), ~1-2 us.
// ---------------------------------------------------------------------------
__global__ void wprep_kernel(const float* __restrict__ W, unsigned short* __restrict__ Wt) {
    int n = blockIdx.x;      // 128
    int k = threadIdx.x;     // 256
    Wt[n * F_DIM + k] = f2bf(W[(size_t)k * E_DIM + n]);
}

// ---------------------------------------------------------------------------
// MFMA bf16 GEMM: h = bf16(A @ W)  (bias cancels in BN), fused column
// sum/sumsq for BN batch stats (fp32-exact from accumulators).
// Block: 128 rows x 128 cols, K staged in 64-wide bf16 chunks.
// 4 waves; wave w computes rows [w*32, w*32+32) x all 128 cols as
// 2x8 tiles of 16x16x32 MFMA. LDS XOR-swizzle: quad q of row r at q^(r&7)
// -> 2-way max bank aliasing on ds_read_b128 (free per m136).
// h stored bf16 via LDS transpose -> coalesced dwordx4 stores.
// ---------------------------------------------------------------------------
__global__ __launch_bounds__(256) void gemm_stats_kernel(
    const float* __restrict__ A, const unsigned short* __restrict__ Wt,
    unsigned short* __restrict__ h, float* __restrict__ gsum, float* __restrict__ gsq)
{
    __shared__ __attribute__((aligned(16))) char smem[32768];
    char* As = smem;            // [128 rows][64 k] bf16, swizzled, 16 KB
    char* Ws = smem + 16384;    // [128 n   ][64 k] bf16, swizzled, 16 KB

    const int t    = threadIdx.x;
    const int lane = t & 63;
    const int wv   = t >> 6;        // wave 0..3
    const int m    = lane & 15;     // row/col within 16-tile
    const int qd   = lane >> 4;     // k-quad 0..3
    const int row0 = blockIdx.x * 128;

    f32x4 acc0[8], acc1[8];
    #pragma unroll
    for (int ct = 0; ct < 8; ++ct) {
        acc0[ct] = (f32x4){0.f, 0.f, 0.f, 0.f};
        acc1[ct] = (f32x4){0.f, 0.f, 0.f, 0.f};
    }

    for (int kk = 0; kk < F_DIM; kk += 64) {
        // ---- stage A chunk [128][64] fp32 -> bf16 LDS (convert in regs) ----
        #pragma unroll
        for (int i = 0; i < 8; ++i) {
            int flat = t + 256 * i;           // 0..2047 float4-slots
            int r  = flat >> 4;               // 0..127
            int c4 = (flat & 15) * 4;         // 0,4,..,60
            int gr = row0 + r; if (gr >= U_NODES) gr = U_NODES - 1;  // clamp (masked later)
            float4 v = *(const float4*)(A + (size_t)gr * F_DIM + kk + c4);
            int q = c4 >> 3, half = (c4 >> 2) & 1;
            ushortx4 w4 = { f2bf(v.x), f2bf(v.y), f2bf(v.z), f2bf(v.w) };
            *(ushortx4*)(As + r * 128 + ((q ^ (r & 7)) << 4) + half * 8) = w4;
        }
        // ---- stage W chunk [128][64] bf16 (already converted) ----
        #pragma unroll
        for (int i = 0; i < 4; ++i) {
            int flat = t + 256 * i;           // 0..1023 ushort8-slots
            int r = flat >> 3, q = flat & 7;
            ushortx8 v = *(const ushortx8*)(Wt + (size_t)r * F_DIM + kk + q * 8);
            *(ushortx8*)(Ws + r * 128 + ((q ^ (r & 7)) << 4)) = v;
        }
        __syncthreads();
        // ---- compute: 2 k-steps of 32, 16 MFMA each ----
        #pragma unroll
        for (int ks = 0; ks < 2; ++ks) {
            int q = ks * 4 + qd;
            int r0 = wv * 32 + m;
            int r1 = r0 + 16;
            bf16x8 a0 = *(const bf16x8*)(As + r0 * 128 + ((q ^ (r0 & 7)) << 4));
            bf16x8 a1 = *(const bf16x8*)(As + r1 * 128 + ((q ^ (r1 & 7)) << 4));
            #pragma unroll
            for (int ct = 0; ct < 8; ++ct) {
                int rb = ct * 16 + m;
                bf16x8 b = *(const bf16x8*)(Ws + rb * 128 + ((q ^ (rb & 7)) << 4));
                acc0[ct] = __builtin_amdgcn_mfma_f32_16x16x32_bf16(a0, b, acc0[ct], 0, 0, 0);
                acc1[ct] = __builtin_amdgcn_mfma_f32_16x16x32_bf16(a1, b, acc1[ct], 0, 0, 0);
            }
        }
        __syncthreads();
    }

    // ---- fused BN stats (mask clamped tail rows) ----
    // D layout (m89-verified): col = lane&15, row = (lane>>4)*4 + reg
    const bool full = (row0 + 128) <= U_NODES;
    float s[8], sq[8];
    #pragma unroll
    for (int ct = 0; ct < 8; ++ct) {
        float ss = 0.f, qq = 0.f;
        #pragma unroll
        for (int v = 0; v < 4; ++v) {
            float x0 = acc0[ct][v];
            float x1 = acc1[ct][v];
            if (full || (row0 + wv * 32 + qd * 4 + v) < U_NODES)      { ss += x0; qq += x0 * x0; }
            if (full || (row0 + wv * 32 + 16 + qd * 4 + v) < U_NODES) { ss += x1; qq += x1 * x1; }
        }
        s[ct] = ss; sq[ct] = qq;
    }
    float* red = (float*)smem;   // [16][128], overlays As (compute done)
    int rq = wv * 4 + qd;
    #pragma unroll
    for (int ct = 0; ct < 8; ++ct) red[rq * 128 + ct * 16 + m] = s[ct];
    __syncthreads();
    if (t < 128) {
        float tot = 0.f;
        #pragma unroll
        for (int i = 0; i < 16; ++i) tot += red[i * 128 + t];
        atomicAdd(&gsum[t], tot);
    }
    __syncthreads();
    #pragma unroll
    for (int ct = 0; ct < 8; ++ct) red[rq * 128 + ct * 16 + m] = sq[ct];
    __syncthreads();
    if (t < 128) {
        float tot = 0.f;
        #pragma unroll
        for (int i = 0; i < 16; ++i) tot += red[i * 128 + t];
        atomicAdd(&gsq[t], tot);
    }
    __syncthreads();

    // ---- h store: AGPR-layout -> LDS transpose -> coalesced bf16x8 stores ----
    unsigned short* tb = (unsigned short*)(smem + wv * 8192);   // [32][128] per wave
    #pragma unroll
    for (int ct = 0; ct < 8; ++ct)
        #pragma unroll
        for (int v = 0; v < 4; ++v) {
            tb[(qd * 4 + v) * 128 + ct * 16 + m]        = f2bf(acc0[ct][v]);
            tb[(16 + qd * 4 + v) * 128 + ct * 16 + m]   = f2bf(acc1[ct][v]);
        }
    __syncthreads();
    #pragma unroll
    for (int i = 0; i < 8; ++i) {
        int idx = lane + 64 * i;            // 0..511
        int r = idx >> 4, c8 = (idx & 15) * 8;
        int gr = row0 + wv * 32 + r;
        if (gr < U_NODES)
            *(ushortx8*)(h + (size_t)gr * E_DIM + c8) = *(const ushortx8*)(tb + r * 128 + c8);
    }
}

// ---------------------------------------------------------------------------
// Fold BN stats + gamma/beta into per-column scale/shift.
// ---------------------------------------------------------------------------
__global__ void finalize_kernel(const float* __restrict__ gsum, const float* __restrict__ gsq,
                                const float* __restrict__ gamma, const float* __restrict__ beta,
                                float* __restrict__ scale, float* __restrict__ shift)
{
    int e = threadIdx.x;
    float mu  = gsum[e] * (1.f / U_NODES);
    float var = gsq[e] * (1.f / U_NODES) - mu * mu;
    float inv = rsqrtf(var + 1e-5f);
    float sc  = gamma[e] * inv;
    scale[e] = sc;
    shift[e] = beta[e] - sc * mu;
}

// ---------------------------------------------------------------------------
// Gather + BN + tanh + mean over K=33. bf16 h rows (256 B): 16 threads/row,
// ushort8 (16 B) per lane, 16 rows per 256-thread block, K fully unrolled
// for deep memory-level parallelism.
// ---------------------------------------------------------------------------
__global__ __launch_bounds__(256) void gather_kernel(
    const unsigned short* __restrict__ h, const int* __restrict__ sidx_g,
    const float* __restrict__ scale, const float* __restrict__ shift,
    float* __restrict__ out)
{
    __shared__ int sl[16 * K_S];
    const int t  = threadIdx.x;
    const int g  = t & 15;          // col group: cols g*8..g*8+7
    const int r  = t >> 4;          // row within block
    const int b0 = blockIdx.x * 16;
    for (int i = t; i < 16 * K_S; i += 256) sl[i] = sidx_g[(size_t)b0 * K_S + i];
    float scv[8], shv[8];
    *(float4*)&scv[0] = *(const float4*)(scale + g * 8);
    *(float4*)&scv[4] = *(const float4*)(scale + g * 8 + 4);
    *(float4*)&shv[0] = *(const float4*)(shift + g * 8);
    *(float4*)&shv[4] = *(const float4*)(shift + g * 8 + 4);
    __syncthreads();

    float acc[8] = {0.f, 0.f, 0.f, 0.f, 0.f, 0.f, 0.f, 0.f};
    #pragma unroll
    for (int k = 0; k < K_S; ++k) {
        int idx = sl[r * K_S + k];
        ushortx8 v = *(const ushortx8*)(h + (size_t)idx * E_DIM + g * 8);
        #pragma unroll
        for (int j = 0; j < 8; ++j) {
            float x  = bf2f(v[j]) * scv[j] + shv[j];
            float ex = __expf(2.f * x);                       // tanh = 1 - 2/(e^2x+1)
            acc[j] += 1.f - 2.f * __builtin_amdgcn_rcpf(ex + 1.f);
        }
    }
    float* op = out + (size_t)(b0 + r) * E_DIM + g * 8;
    *(float4*)(op)     = make_float4(acc[0] * (1.f / K_S), acc[1] * (1.f / K_S),
                                     acc[2] * (1.f / K_S), acc[3] * (1.f / K_S));
    *(float4*)(op + 4) = make_float4(acc[4] * (1.f / K_S), acc[5] * (1.f / K_S),
                                     acc[6] * (1.f / K_S), acc[7] * (1.f / K_S));
}

// ---------------------------------------------------------------------------
extern "C" void kernel_launch(void* const* d_in, const int* in_sizes, int n_in,
                              void* d_out, int out_size, void* d_ws, size_t ws_size,
                              hipStream_t stream) {
    const float* features = (const float*)d_in[0];
    const float* W        = (const float*)d_in[1];
    // d_in[2] = bias — provably cancels inside BatchNorm; unused.
    const float* gamma    = (const float*)d_in[3];
    const float* beta     = (const float*)d_in[4];
    const int*   sample   = (const int*)d_in[5];
    float* out = (float*)d_out;

    // ws layout: gsum[128] gsq[128] scale[128] shift[128] | Wt[128*256 bf16] | h[U*128 bf16]
    float* gsum  = (float*)d_ws;
    float* gsq   = gsum + 128;
    float* scale = gsq + 128;
    float* shift = scale + 128;
    unsigned short* Wt = (unsigned short*)(shift + 128);
    unsigned short* h  = Wt + 128 * 256;        // byte offset 67584, 16B-aligned

    hipMemsetAsync(gsum, 0, 2 * 128 * sizeof(float), stream);
    wprep_kernel<<<128, 256, 0, stream>>>(W, Wt);
    gemm_stats_kernel<<<(U_NODES + 127) / 128, 256, 0, stream>>>(features, Wt, h, gsum, gsq);
    finalize_kernel<<<1, 128, 0, stream>>>(gsum, gsq, gamma, beta, scale, shift);
    gather_kernel<<<B_ROWS / 16, 256, 0, stream>>>(h, sample, scale, shift, out);
}